// Round 2
// baseline (34.021 us; speedup 1.0000x reference)
//
#include <hip/hip_runtime.h>
#include <hip/hip_bf16.h>

// Problem: S=128, Q=8192, H=230
//   logits[s,q] = sum_h w[h]*(x[s,h]-y[q,h])^2 + b
//               = a[s] - 2*sum_h (w*x)[s,h]*y[q,h] + c[q] + b
// Folded into a single K=232 dot product:
//   XW[s][0..229] = w*x,  XW[s][230] = a[s],          XW[s][231] = 1
//   YL[q][0..229] = y,    YL[q][230] = -0.5,          YL[q][231] = -0.5*(c[q]+b)
//   logits = -2 * dot232(XW[s], YL[q])
// Outputs: score = sigmoid(logits) flattened [S*Q], then loss (mean BCE) at [S*Q].
// Loss reduction is 3-stage and order-fixed for determinism (graph replay
// must be bitwise-identical to launch_once).

#define S_DIM 128
#define Q_DIM 8192
#define H_DIM 230
#define K_PAD 232
#define SQ (S_DIM * Q_DIM)
#define QB 32                 // q-tile per block in main kernel
#define NBLK (Q_DIM / QB)     // 256 main blocks

// ---------------- Kernel 1: prep ----------------
// grid = 128 (one block per s-row), block = 256
__global__ __launch_bounds__(256) void prep_kernel(
    const float* __restrict__ x, const float* __restrict__ w,
    float* __restrict__ xw, float* __restrict__ ww)
{
    __shared__ float lred[4];
    const int tid = threadIdx.x;
    const int s = blockIdx.x;

    float xv = 0.f, wv = 0.f;
    if (tid < H_DIM) {
        xv = x[s * H_DIM + tid];
        wv = w[tid];
    }
    float prod = xv * wv;                 // (w*x)[s,h]
    if (tid < H_DIM) xw[s * K_PAD + tid] = prod;
    if (tid == 231)  xw[s * K_PAD + 231] = 1.0f;

    if (s == 0 && tid < K_PAD) ww[tid] = (tid < H_DIM) ? w[tid] : 0.0f;

    // a[s] = sum_h w*x^2  (block reduce over 256 threads; >=230 contribute 0)
    float p = prod * xv;
    #pragma unroll
    for (int off = 32; off >= 1; off >>= 1) p += __shfl_down(p, off, 64);
    if ((tid & 63) == 0) lred[tid >> 6] = p;
    __syncthreads();
    if (tid == 0) xw[s * K_PAD + 230] = lred[0] + lred[1] + lred[2] + lred[3];
}

// ---------------- Kernel 2: main fused GEMM + sigmoid + BCE ----------------
// grid = Q/QB = 256, block = 256.  Each block: all 128 s  x  32 q.
// Thread (tx = tid&7 over q-groups, ty = tid>>3 over s-groups), 4x4 register tile:
//   q = q0 + tx + 8*j (j=0..3),  s = ty + 32*i (i=0..3)
__global__ __launch_bounds__(256) void main_kernel(
    const float* __restrict__ y, const int* __restrict__ label,
    const float* __restrict__ xw, const float* __restrict__ ww,
    const float* __restrict__ bptr, float* __restrict__ out,
    float* __restrict__ lossws)
{
    __shared__ float yl[QB][K_PAD];     // 32x232 f32 = 29.7 KB
    __shared__ float cpart[8][32];
    __shared__ float wl[K_PAD];
    __shared__ float lred[4];

    const int tid = threadIdx.x;
    const int q0 = blockIdx.x * QB;

    if (tid < K_PAD) wl[tid] = ww[tid];

    // Stage y tile: rows are contiguous, so the whole tile is one contiguous
    // span of 32*230 = 7360 floats = 1840 float4 starting at y + q0*230.
    const float* ysrc = y + (size_t)q0 * H_DIM;
    for (int i4 = tid; i4 < (QB * H_DIM) / 4; i4 += 256) {
        float4 v = ((const float4*)ysrc)[i4];
        float vv[4] = {v.x, v.y, v.z, v.w};
        int e = i4 * 4;
        #pragma unroll
        for (int k = 0; k < 4; ++k) {
            int ee = e + k;
            int r = ee / H_DIM;
            int c = ee - r * H_DIM;
            yl[r][c] = vv[k];
        }
    }
    __syncthreads();

    // c[q] = sum_h w[h]*y[q,h]^2   (8 threads per q, then LDS reduce)
    {
        const int q = tid & 31, part = tid >> 5;
        const int h0 = part * 29;
        const int h1 = (h0 + 29 < H_DIM) ? h0 + 29 : H_DIM;
        float p = 0.f;
        for (int h = h0; h < h1; ++h) {
            float v = yl[q][h];
            p = fmaf(wl[h] * v, v, p);
        }
        cpart[part][q] = p;
    }
    __syncthreads();
    if (tid < QB) {
        float c = 0.f;
        #pragma unroll
        for (int p = 0; p < 8; ++p) c += cpart[p][tid];
        float bb = bptr[0];
        yl[tid][230] = -0.5f;
        yl[tid][231] = -0.5f * (c + bb);
    }
    __syncthreads();

    // Register-tiled dot products over K=232.
    const int tx = tid & 7;    // q-group
    const int ty = tid >> 3;   // s-group (0..31)
    float acc[4][4] = {};
    const float* xwbase = xw + ty * K_PAD;

    #pragma unroll 2
    for (int kk = 0; kk < K_PAD; kk += 4) {
        float4 yv[4], xv[4];
        #pragma unroll
        for (int j = 0; j < 4; ++j)
            yv[j] = *(const float4*)&yl[tx + 8 * j][kk];
        #pragma unroll
        for (int i = 0; i < 4; ++i)
            xv[i] = *(const float4*)(xwbase + i * 32 * K_PAD + kk);
        #pragma unroll
        for (int i = 0; i < 4; ++i)
            #pragma unroll
            for (int j = 0; j < 4; ++j)
                acc[i][j] = fmaf(xv[i].x, yv[j].x,
                            fmaf(xv[i].y, yv[j].y,
                            fmaf(xv[i].z, yv[j].z,
                            fmaf(xv[i].w, yv[j].w, acc[i][j]))));
    }

    // Epilogue: sigmoid -> out, BCE -> block-reduced partial (fixed order).
    float lsum = 0.f;
    #pragma unroll
    for (int i = 0; i < 4; ++i) {
        const int s = ty + 32 * i;
        const size_t rowoff = (size_t)s * Q_DIM + q0;
        #pragma unroll
        for (int j = 0; j < 4; ++j) {
            const int q = tx + 8 * j;
            float z = -2.0f * acc[i][j];
            float sc = 1.0f / (1.0f + __expf(-z));
            out[rowoff + q] = sc;
            float lab = (float)label[rowoff + q];
            // bce = softplus(z) - lab*z, stable form
            float bce = fmaxf(z, 0.f) - z * lab + log1pf(__expf(-fabsf(z)));
            lsum += bce;
        }
    }
    #pragma unroll
    for (int off = 32; off >= 1; off >>= 1) lsum += __shfl_down(lsum, off, 64);
    if ((tid & 63) == 0) lred[tid >> 6] = lsum;
    __syncthreads();
    if (tid == 0)
        lossws[blockIdx.x] = lred[0] + lred[1] + lred[2] + lred[3];
}

// ---------------- Kernel 3: deterministic loss reduce ----------------
// 1 block, 256 threads; fixed-order tree reduce of NBLK=256 partials.
__global__ __launch_bounds__(256) void loss_reduce_kernel(
    const float* __restrict__ lossws, float* __restrict__ out)
{
    __shared__ float lred[4];
    const int tid = threadIdx.x;
    float p = lossws[tid];
    #pragma unroll
    for (int off = 32; off >= 1; off >>= 1) p += __shfl_down(p, off, 64);
    if ((tid & 63) == 0) lred[tid >> 6] = p;
    __syncthreads();
    if (tid == 0)
        out[SQ] = (lred[0] + lred[1] + lred[2] + lred[3]) * (1.0f / (float)SQ);
}

extern "C" void kernel_launch(void* const* d_in, const int* in_sizes, int n_in,
                              void* d_out, int out_size, void* d_ws, size_t ws_size,
                              hipStream_t stream) {
    const float* x = (const float*)d_in[0];     // [128,230]
    const float* y = (const float*)d_in[1];     // [8192,230]
    const int* label = (const int*)d_in[2];     // [128,8192]
    const float* w = (const float*)d_in[3];     // [230]
    const float* b = (const float*)d_in[4];     // [1]
    float* out = (float*)d_out;                 // [128*8192 + 1]

    float* xw = (float*)d_ws;                   // [128][232]
    float* ww = xw + S_DIM * K_PAD;             // [232]
    float* lossws = ww + K_PAD;                 // [256]

    prep_kernel<<<S_DIM, 256, 0, stream>>>(x, w, xw, ww);
    main_kernel<<<NBLK, 256, 0, stream>>>(y, label, xw, ww, b, out, lossws);
    loss_reduce_kernel<<<1, 256, 0, stream>>>(lossws, out);
}

// Round 3
// 23.414 us; speedup vs baseline: 1.4530x; 1.4530x over previous
//
#include <hip/hip_runtime.h>
#include <hip/hip_bf16.h>

// S=128, Q=8192, H=230
//   logits[s,q] = a[s] + c[q] + b - 2*sum_k wx[s,k]*y[q,k]
//   a[s]=sum w*x^2 (f32), c[q]=sum w*y^2 (f32), dot via bf16 MFMA (f32 acc).
// Outputs: score=sigmoid(logits) [S*Q] then mean BCE at out[S*Q].
// All reductions fixed-order (graph replay must be bitwise identical).

#define S_DIM 128
#define Q_DIM 8192
#define H_DIM 230
#define K2    256              // bf16 K padded to multiple of 32
#define SQ    (S_DIM * Q_DIM)
#define QB    16               // q-tile per block
#define NBLK  (Q_DIM / QB)     // 512 main blocks

using short8 = __attribute__((ext_vector_type(8))) short;   // 8 bf16 (4 VGPRs)
using f32x4  = __attribute__((ext_vector_type(4))) float;

// ---------------- Kernel 1: prep ----------------
// grid=128, block=256(==K2). xwb[s][k]=bf16(w*x), zero-padded; asum[s]=sum w*x^2.
__global__ __launch_bounds__(256) void prep_kernel(
    const float* __restrict__ x, const float* __restrict__ w,
    __hip_bfloat16* __restrict__ xwb, float* __restrict__ asum)
{
    __shared__ float lred[4];
    const int tid = threadIdx.x, s = blockIdx.x;
    float xv = 0.f, wv = 0.f;
    if (tid < H_DIM) { xv = x[s * H_DIM + tid]; wv = w[tid]; }
    float wx = wv * xv;
    xwb[s * K2 + tid] = __float2bfloat16(wx);   // 0 for tid>=230

    float p = wx * xv;                          // w*x^2
    #pragma unroll
    for (int off = 32; off >= 1; off >>= 1) p += __shfl_down(p, off, 64);
    if ((tid & 63) == 0) lred[tid >> 6] = p;
    __syncthreads();
    if (tid == 0) asum[s] = lred[0] + lred[1] + lred[2] + lred[3];
}

// ---------------- Kernel 2: main (MFMA GEMM + sigmoid + BCE) ----------------
// grid=512, block=256 (4 waves). Block: all 128 s x 16 q. Wave w: s in [32w,32w+32).
__global__ __launch_bounds__(256) void main_kernel(
    const float* __restrict__ y, const int* __restrict__ label,
    const __hip_bfloat16* __restrict__ xwb, const float* __restrict__ asum,
    const float* __restrict__ w, const float* __restrict__ bptr,
    float* __restrict__ out, float* __restrict__ lossws)
{
    __shared__ __align__(16) short ylb[QB * K2];   // 8 KB bf16, XOR-swizzled
    __shared__ float cpart[16][17];
    __shared__ float cq[QB];
    __shared__ float asl[S_DIM];
    __shared__ float lred[4];

    const int tid = threadIdx.x;
    const int q0 = blockIdx.x * QB;

    if (tid < S_DIM) asl[tid] = asum[tid];

    // ---- stage y tile (16 rows x 230 f32) -> bf16 swizzled LDS ----
    // Tile is one contiguous span: q0*230 f32, 16B-aligned (q0*920 % 16 == 0).
    const float4* ysrc4 = reinterpret_cast<const float4*>(y + (size_t)q0 * H_DIM);
    char* ylc = reinterpret_cast<char*>(ylb);
    #pragma unroll
    for (int it = 0; it < 4; ++it) {
        int i4 = tid + 256 * it;
        if (i4 < (QB * H_DIM) / 4) {
            float4 v = ysrc4[i4];
            float vv[4] = {v.x, v.y, v.z, v.w};
            #pragma unroll
            for (int j = 0; j < 4; ++j) {
                int ee = i4 * 4 + j;
                int r = ee / H_DIM;            // const divide -> magic mul
                int c = ee - r * H_DIM;
                int byt = ((r << 9) + (c << 1)) ^ ((r & 7) << 4);
                *reinterpret_cast<__hip_bfloat16*>(ylc + byt) = __float2bfloat16(vv[j]);
            }
        }
    }
    {   // zero-fill k = 230..255
        const int r = tid & 15;
        for (int c = H_DIM + (tid >> 4); c < K2; c += 16) {
            int byt = ((r << 9) + (c << 1)) ^ ((r & 7) << 4);
            *reinterpret_cast<__hip_bfloat16*>(ylc + byt) = __float2bfloat16(0.0f);
        }
    }
    __syncthreads();

    // ---- c[q] = sum_k w[k]*y~[q,k]^2 from the bf16 tile ----
    {
        const int r = tid & 15, ch = tid >> 4;
        const int k0 = ch * 16;
        float p = 0.f;
        #pragma unroll
        for (int j = 0; j < 16; ++j) {
            int k = k0 + j;
            int byt = ((r << 9) + (k << 1)) ^ ((r & 7) << 4);
            float v = __bfloat162float(*reinterpret_cast<__hip_bfloat16*>(ylc + byt));
            float wk = (k < H_DIM) ? w[k] : 0.f;   // broadcast across 16 lanes
            p = fmaf(wk * v, v, p);
        }
        cpart[ch][r] = p;
    }
    __syncthreads();
    if (tid < QB) {
        float c = 0.f;
        #pragma unroll
        for (int ch = 0; ch < 16; ++ch) c += cpart[ch][tid];
        cq[tid] = c + bptr[0];                     // fold bias in
    }
    __syncthreads();

    // ---- MFMA k-loop: wave computes 32 s x 16 q ----
    const int l  = tid & 63, wid = tid >> 6;
    const int lm = l & 15,   lh  = l >> 4;         // lh in 0..3
    f32x4 acc0 = {0.f, 0.f, 0.f, 0.f};
    f32x4 acc1 = {0.f, 0.f, 0.f, 0.f};
    const short* xwp = reinterpret_cast<const short*>(xwb);
    const int arow0 = (wid * 32 + lm) * K2;        // A rows [32w, 32w+16)
    const int arow1 = arow0 + 16 * K2;             // A rows [32w+16, 32w+32)
    #pragma unroll
    for (int ks = 0; ks < K2 / 32; ++ks) {
        const int kof = ks * 32 + lh * 8;
        short8 a0 = *reinterpret_cast<const short8*>(xwp + arow0 + kof);
        short8 a1 = *reinterpret_cast<const short8*>(xwp + arow1 + kof);
        int byt = ((lm << 9) + (kof << 1)) ^ ((lm & 7) << 4);
        short8 bf = *reinterpret_cast<const short8*>(ylc + byt);
        acc0 = __builtin_amdgcn_mfma_f32_16x16x32_bf16(a0, bf, acc0, 0, 0, 0);
        acc1 = __builtin_amdgcn_mfma_f32_16x16x32_bf16(a1, bf, acc1, 0, 0, 0);
    }

    // ---- epilogue: z = a[s]+c[q]+b-2*dot ; sigmoid -> out ; BCE partial ----
    float lsum = 0.f;
    const int qg = q0 + lm;
    #pragma unroll
    for (int f = 0; f < 2; ++f) {
        f32x4 ac = f ? acc1 : acc0;
        #pragma unroll
        for (int r = 0; r < 4; ++r) {
            int s = wid * 32 + f * 16 + lh * 4 + r;   // D row=(l>>4)*4+r, col=l&15
            float z = asl[s] + cq[lm] - 2.0f * ac[r];
            float sc = 1.0f / (1.0f + __expf(-z));
            size_t o = (size_t)s * Q_DIM + qg;
            out[o] = sc;
            float lab = (float)label[o];
            float bce = fmaxf(z, 0.f) - z * lab + log1pf(__expf(-fabsf(z)));
            lsum += bce;
        }
    }
    #pragma unroll
    for (int off = 32; off >= 1; off >>= 1) lsum += __shfl_down(lsum, off, 64);
    if (l == 0) lred[wid] = lsum;
    __syncthreads();
    if (tid == 0)
        lossws[blockIdx.x] = lred[0] + lred[1] + lred[2] + lred[3];
}

// ---------------- Kernel 3: deterministic loss reduce ----------------
__global__ __launch_bounds__(256) void loss_reduce_kernel(
    const float* __restrict__ lossws, float* __restrict__ out)
{
    __shared__ float lred[4];
    const int tid = threadIdx.x;
    float p = lossws[tid] + lossws[tid + 256];     // NBLK=512 partials
    #pragma unroll
    for (int off = 32; off >= 1; off >>= 1) p += __shfl_down(p, off, 64);
    if ((tid & 63) == 0) lred[tid >> 6] = p;
    __syncthreads();
    if (tid == 0)
        out[SQ] = (lred[0] + lred[1] + lred[2] + lred[3]) * (1.0f / (float)SQ);
}

extern "C" void kernel_launch(void* const* d_in, const int* in_sizes, int n_in,
                              void* d_out, int out_size, void* d_ws, size_t ws_size,
                              hipStream_t stream) {
    const float* x = (const float*)d_in[0];     // [128,230]
    const float* y = (const float*)d_in[1];     // [8192,230]
    const int* label = (const int*)d_in[2];     // [128,8192]
    const float* w = (const float*)d_in[3];     // [230]
    const float* b = (const float*)d_in[4];     // [1]
    float* out = (float*)d_out;                 // [128*8192 + 1]

    __hip_bfloat16* xwb = (__hip_bfloat16*)d_ws;            // [128][256] bf16 = 64 KB
    float* asum = (float*)((char*)d_ws + S_DIM * K2 * 2);   // [128]
    float* lossws = asum + S_DIM;                           // [512]

    prep_kernel<<<S_DIM, 256, 0, stream>>>(x, w, xwb, asum);
    main_kernel<<<NBLK, 256, 0, stream>>>(y, label, xwb, asum, w, b, out, lossws);
    loss_reduce_kernel<<<1, 256, 0, stream>>>(lossws, out);
}